// Round 1
// baseline (119.941 us; speedup 1.0000x reference)
//
#include <hip/hip_runtime.h>
#include <hip/hip_bf16.h>

typedef __bf16 bf16x8 __attribute__((ext_vector_type(8)));
typedef float  f32x4  __attribute__((ext_vector_type(4)));

#define NN 4096
#define DK 128
#define BM 128
#define BN 128
#define EPSF 1e-10f
#define NMAX 0.99f

__global__ __launch_bounds__(256, 2)
void hyp_dist_kernel(const float* __restrict__ X, const float* __restrict__ Y,
                     float* __restrict__ Out)
{
    __shared__ alignas(16) __bf16 aL[BM * DK];
    __shared__ alignas(16) __bf16 bL[BN * DK];
    __shared__ float xsL[BM];
    __shared__ float ysL[BN];

    const int tid  = threadIdx.x;
    const int bz   = blockIdx.z;
    const int brow = blockIdx.y * BM;
    const int bcol = blockIdx.x * BN;

    const float* xb = X + ((size_t)bz * NN + brow) * DK;
    const float* yb = Y + ((size_t)bz * NN + bcol) * DK;

    const int c16 = tid & 15;   // 16B (8-elem) chunk within a row
    const int rr  = tid >> 4;   // 16 rows per pass

    // Stage x-tile and y-tile: f32 global -> bf16 LDS (swizzled), and
    // compute per-row sum of squares in f32 via 16-lane shfl reduction.
#pragma unroll
    for (int p = 0; p < 8; ++p) {
        const int r = p * 16 + rr;
        {
            const f32x4* s4 = (const f32x4*)(xb + r * DK + c16 * 8);
            f32x4 v0 = s4[0], v1 = s4[1];
            float s = v0[0]*v0[0] + v0[1]*v0[1] + v0[2]*v0[2] + v0[3]*v0[3]
                    + v1[0]*v1[0] + v1[1]*v1[1] + v1[2]*v1[2] + v1[3]*v1[3];
            s += __shfl_xor(s, 1);
            s += __shfl_xor(s, 2);
            s += __shfl_xor(s, 4);
            s += __shfl_xor(s, 8);
            if (c16 == 0) xsL[r] = s;
            bf16x8 pk;
            pk[0]=(__bf16)v0[0]; pk[1]=(__bf16)v0[1]; pk[2]=(__bf16)v0[2]; pk[3]=(__bf16)v0[3];
            pk[4]=(__bf16)v1[0]; pk[5]=(__bf16)v1[1]; pk[6]=(__bf16)v1[2]; pk[7]=(__bf16)v1[3];
            const int byt = (r * 256 + c16 * 16) ^ ((r & 7) << 4);
            *(bf16x8*)((char*)aL + byt) = pk;
        }
        {
            const f32x4* s4 = (const f32x4*)(yb + r * DK + c16 * 8);
            f32x4 v0 = s4[0], v1 = s4[1];
            float s = v0[0]*v0[0] + v0[1]*v0[1] + v0[2]*v0[2] + v0[3]*v0[3]
                    + v1[0]*v1[0] + v1[1]*v1[1] + v1[2]*v1[2] + v1[3]*v1[3];
            s += __shfl_xor(s, 1);
            s += __shfl_xor(s, 2);
            s += __shfl_xor(s, 4);
            s += __shfl_xor(s, 8);
            if (c16 == 0) ysL[r] = s;
            bf16x8 pk;
            pk[0]=(__bf16)v0[0]; pk[1]=(__bf16)v0[1]; pk[2]=(__bf16)v0[2]; pk[3]=(__bf16)v0[3];
            pk[4]=(__bf16)v1[0]; pk[5]=(__bf16)v1[1]; pk[6]=(__bf16)v1[2]; pk[7]=(__bf16)v1[3];
            const int byt = (r * 256 + c16 * 16) ^ ((r & 7) << 4);
            *(bf16x8*)((char*)bL + byt) = pk;
        }
    }
    __syncthreads();

    const int lane = tid & 63;
    const int wid  = tid >> 6;
    const int wm   = wid >> 1;   // 2x2 wave grid, each wave: 64x64 output
    const int wn   = wid & 1;
    const int r16  = lane & 15;
    const int kg   = lane >> 4;

    f32x4 acc[4][4] = {};

#pragma unroll
    for (int ks = 0; ks < 4; ++ks) {
        const int kb = ks * 32 + kg * 8;     // element k-offset for this lane
        bf16x8 af[4], bg[4];
#pragma unroll
        for (int i = 0; i < 4; ++i) {
            const int r = wm * 64 + i * 16 + r16;
            const int byt = (r * 256 + kb * 2) ^ ((r & 7) << 4);
            af[i] = *(const bf16x8*)((const char*)aL + byt);
        }
#pragma unroll
        for (int j = 0; j < 4; ++j) {
            const int r = wn * 64 + j * 16 + r16;
            const int byt = (r * 256 + kb * 2) ^ ((r & 7) << 4);
            bg[j] = *(const bf16x8*)((const char*)bL + byt);
        }
#pragma unroll
        for (int i = 0; i < 4; ++i)
#pragma unroll
            for (int j = 0; j < 4; ++j)
                acc[i][j] = __builtin_amdgcn_mfma_f32_16x16x32_bf16(af[i], bg[j], acc[i][j], 0, 0, 0);
    }

    // Epilogue: C/D layout col = lane&15, row = (lane>>4)*4 + reg (m89-verified).
    float* ob = Out + ((size_t)bz * NN + brow) * NN + bcol;
#pragma unroll
    for (int i = 0; i < 4; ++i) {
#pragma unroll
        for (int q = 0; q < 4; ++q) {
            const int r = wm * 64 + i * 16 + kg * 4 + q;
            const float xsr = xsL[r];
            const float Bv  = 1.0f - xsr;
            float* orow = ob + (size_t)r * NN;
#pragma unroll
            for (int j = 0; j < 4; ++j) {
                const int c = wn * 64 + j * 16 + r16;
                const float dot = acc[i][j][q];
                const float ysc = ysL[c];
                const float Av  = 1.0f - 2.0f * dot + ysc;
                const float den = 1.0f - 2.0f * dot + xsr * ysc;
                float num = Av * Av * xsr - 2.0f * Av * Bv * dot + Bv * Bv * ysc;
                num = fmaxf(num, 0.0f);
                float dn = __builtin_amdgcn_sqrtf(num) *
                           __builtin_amdgcn_rcpf(fmaxf(den, EPSF));
                dn = fminf(fmaxf(dn, EPSF), NMAX);
                // 2*atanh(z) = ln((1+z)/(1-z))
                orow[c] = __logf((1.0f + dn) * __builtin_amdgcn_rcpf(1.0f - dn));
            }
        }
    }
}

extern "C" void kernel_launch(void* const* d_in, const int* in_sizes, int n_in,
                              void* d_out, int out_size, void* d_ws, size_t ws_size,
                              hipStream_t stream) {
    const float* X = (const float*)d_in[0];
    const float* Y = (const float*)d_in[1];
    float* O = (float*)d_out;
    const int b = in_sizes[0] / (NN * DK);   // = 4
    dim3 grid(NN / BN, NN / BM, b);
    hyp_dist_kernel<<<grid, dim3(256), 0, stream>>>(X, Y, O);
}

// Round 2
// 111.963 us; speedup vs baseline: 1.0713x; 1.0713x over previous
//
#include <hip/hip_runtime.h>
#include <hip/hip_bf16.h>

typedef __bf16 bf16x8 __attribute__((ext_vector_type(8)));
typedef float  f32x4  __attribute__((ext_vector_type(4)));

#define NN 4096
#define DK 128
#define BM 128
#define BN 128
#define NMAX 0.99f

__global__ __launch_bounds__(256, 2)
void hyp_dist_kernel(const float* __restrict__ X, const float* __restrict__ Y,
                     float* __restrict__ Out)
{
    __shared__ alignas(16) __bf16 aL[BM * DK];
    __shared__ alignas(16) __bf16 bL[BN * DK];
    __shared__ float xsL[BM];
    __shared__ float ysL[BN];

    const int tid  = threadIdx.x;
    const int bz   = blockIdx.z;
    const int brow = blockIdx.y * BM;
    const int bcol = blockIdx.x * BN;

    const float* xb = X + ((size_t)bz * NN + brow) * DK;
    const float* yb = Y + ((size_t)bz * NN + bcol) * DK;

    const int c16 = tid & 15;   // 16B (8-elem) chunk within a row
    const int rr  = tid >> 4;   // 16 rows per pass

    // Stage x-tile and y-tile: f32 global -> bf16 LDS (swizzled), and
    // compute per-row sum of squares in f32 via 16-lane shfl reduction.
#pragma unroll
    for (int p = 0; p < 8; ++p) {
        const int r = p * 16 + rr;
        {
            const f32x4* s4 = (const f32x4*)(xb + r * DK + c16 * 8);
            f32x4 v0 = s4[0], v1 = s4[1];
            float s = v0[0]*v0[0] + v0[1]*v0[1] + v0[2]*v0[2] + v0[3]*v0[3]
                    + v1[0]*v1[0] + v1[1]*v1[1] + v1[2]*v1[2] + v1[3]*v1[3];
            s += __shfl_xor(s, 1);
            s += __shfl_xor(s, 2);
            s += __shfl_xor(s, 4);
            s += __shfl_xor(s, 8);
            if (c16 == 0) xsL[r] = s;
            bf16x8 pk;
            pk[0]=(__bf16)v0[0]; pk[1]=(__bf16)v0[1]; pk[2]=(__bf16)v0[2]; pk[3]=(__bf16)v0[3];
            pk[4]=(__bf16)v1[0]; pk[5]=(__bf16)v1[1]; pk[6]=(__bf16)v1[2]; pk[7]=(__bf16)v1[3];
            const int byt = (r * 256 + c16 * 16) ^ ((r & 7) << 4);
            *(bf16x8*)((char*)aL + byt) = pk;
        }
        {
            const f32x4* s4 = (const f32x4*)(yb + r * DK + c16 * 8);
            f32x4 v0 = s4[0], v1 = s4[1];
            float s = v0[0]*v0[0] + v0[1]*v0[1] + v0[2]*v0[2] + v0[3]*v0[3]
                    + v1[0]*v1[0] + v1[1]*v1[1] + v1[2]*v1[2] + v1[3]*v1[3];
            s += __shfl_xor(s, 1);
            s += __shfl_xor(s, 2);
            s += __shfl_xor(s, 4);
            s += __shfl_xor(s, 8);
            if (c16 == 0) ysL[r] = s;
            bf16x8 pk;
            pk[0]=(__bf16)v0[0]; pk[1]=(__bf16)v0[1]; pk[2]=(__bf16)v0[2]; pk[3]=(__bf16)v0[3];
            pk[4]=(__bf16)v1[0]; pk[5]=(__bf16)v1[1]; pk[6]=(__bf16)v1[2]; pk[7]=(__bf16)v1[3];
            const int byt = (r * 256 + c16 * 16) ^ ((r & 7) << 4);
            *(bf16x8*)((char*)bL + byt) = pk;
        }
    }
    __syncthreads();

    const int lane = tid & 63;
    const int wid  = tid >> 6;
    const int wm   = wid >> 1;   // 2x2 wave grid, each wave: 64x64 output
    const int wn   = wid & 1;
    const int r16  = lane & 15;
    const int kg   = lane >> 4;

    f32x4 acc[4][4] = {};

#pragma unroll
    for (int ks = 0; ks < 4; ++ks) {
        const int kb = ks * 32 + kg * 8;     // element k-offset for this lane
        bf16x8 af[4], bg[4];
#pragma unroll
        for (int i = 0; i < 4; ++i) {
            const int r = wm * 64 + i * 16 + r16;
            const int byt = (r * 256 + kb * 2) ^ ((r & 7) << 4);
            af[i] = *(const bf16x8*)((const char*)aL + byt);
        }
#pragma unroll
        for (int j = 0; j < 4; ++j) {
            const int r = wn * 64 + j * 16 + r16;
            const int byt = (r * 256 + kb * 2) ^ ((r & 7) << 4);
            bg[j] = *(const bf16x8*)((const char*)bL + byt);
        }
        // Swapped operands: D[row][col] = dot(y_row, x_col) so the C/D
        // mapping (row=(lane>>4)*4+reg, col=lane&15) puts each lane's 4
        // regs on 4 CONSECUTIVE OUTPUT COLUMNS of one output row.
#pragma unroll
        for (int i = 0; i < 4; ++i)
#pragma unroll
            for (int j = 0; j < 4; ++j)
                acc[i][j] = __builtin_amdgcn_mfma_f32_16x16x32_bf16(bg[j], af[i], acc[i][j], 0, 0, 0);
    }

    // Epilogue. Identity: num_sq = den * s with s = xs + ys - 2*dot,
    // so diff_norm = sqrt(s/den) = s * rsqrt(s*den).
    // Lane owns output row r = wm*64+i*16+(lane&15), cols cb..cb+3,
    // cb = wn*64 + j*16 + (lane>>4)*4  -> f32x4 stores.
    float* ob = Out + ((size_t)bz * NN + brow) * NN + bcol;
#pragma unroll
    for (int i = 0; i < 4; ++i) {
        const int r = wm * 64 + i * 16 + r16;
        const float u = xsL[r];
        float* orow = ob + (size_t)r * NN;
#pragma unroll
        for (int j = 0; j < 4; ++j) {
            const int cb = wn * 64 + j * 16 + kg * 4;
            const f32x4 v4 = *(const f32x4*)&ysL[cb];
            f32x4 o4;
#pragma unroll
            for (int q = 0; q < 4; ++q) {
                const float d  = acc[i][j][q];
                const float v  = v4[q];
                const float e1 = fmaf(-2.0f, d, 1.0f);      // 1 - 2d
                const float den = fmaf(u, v, e1);           // 1 - 2d + u*v
                float s = fmaf(-2.0f, d, u + v);            // u + v - 2d
                s = fmaxf(s, 1e-12f);
                const float t  = s * den;
                const float dn0 = s * __builtin_amdgcn_rsqf(t);   // sqrt(s/den)
                const float dn = fminf(dn0, NMAX);
                // 2*atanh(z) = ln((1+z)/(1-z))
                o4[q] = __logf((1.0f + dn) * __builtin_amdgcn_rcpf(1.0f - dn));
            }
            *(f32x4*)(orow + cb) = o4;
        }
    }
}

extern "C" void kernel_launch(void* const* d_in, const int* in_sizes, int n_in,
                              void* d_out, int out_size, void* d_ws, size_t ws_size,
                              hipStream_t stream) {
    const float* X = (const float*)d_in[0];
    const float* Y = (const float*)d_in[1];
    float* O = (float*)d_out;
    const int b = in_sizes[0] / (NN * DK);   // = 4
    dim3 grid(NN / BN, NN / BM, b);
    hyp_dist_kernel<<<grid, dim3(256), 0, stream>>>(X, Y, O);
}

// Round 3
// 100.268 us; speedup vs baseline: 1.1962x; 1.1166x over previous
//
#include <hip/hip_runtime.h>
#include <hip/hip_bf16.h>

typedef __bf16 bf16x8 __attribute__((ext_vector_type(8)));
typedef float  f32x4  __attribute__((ext_vector_type(4)));

#define NN 4096
#define DK 128
#define BM 128
#define BN 128
#define NMAX 0.99f

__global__ __launch_bounds__(512, 4)
void hyp_dist_kernel(const float* __restrict__ X, const float* __restrict__ Y,
                     float* __restrict__ Out)
{
    __shared__ alignas(16) __bf16 aL[BM * DK];
    __shared__ alignas(16) __bf16 bL[BN * DK];
    __shared__ float xsL[BM];
    __shared__ float ysL[BN];

    const int tid  = threadIdx.x;
    const int bz   = blockIdx.z;
    const int brow = blockIdx.y * BM;
    const int bcol = blockIdx.x * BN;

    const float* xb = X + ((size_t)bz * NN + brow) * DK;
    const float* yb = Y + ((size_t)bz * NN + bcol) * DK;

    const int c16 = tid & 15;   // 16B (8-elem) chunk within a row
    const int rr  = tid >> 4;   // 32 rows per pass (512 threads)

    // Stage x-tile and y-tile: f32 global -> bf16 LDS (swizzled), and
    // compute per-row sum of squares in f32 via 16-lane shfl reduction.
#pragma unroll
    for (int p = 0; p < 4; ++p) {
        const int r = p * 32 + rr;
        {
            const f32x4* s4 = (const f32x4*)(xb + r * DK + c16 * 8);
            f32x4 v0 = s4[0], v1 = s4[1];
            float s = v0[0]*v0[0] + v0[1]*v0[1] + v0[2]*v0[2] + v0[3]*v0[3]
                    + v1[0]*v1[0] + v1[1]*v1[1] + v1[2]*v1[2] + v1[3]*v1[3];
            s += __shfl_xor(s, 1);
            s += __shfl_xor(s, 2);
            s += __shfl_xor(s, 4);
            s += __shfl_xor(s, 8);
            if (c16 == 0) xsL[r] = s;
            bf16x8 pk;
            pk[0]=(__bf16)v0[0]; pk[1]=(__bf16)v0[1]; pk[2]=(__bf16)v0[2]; pk[3]=(__bf16)v0[3];
            pk[4]=(__bf16)v1[0]; pk[5]=(__bf16)v1[1]; pk[6]=(__bf16)v1[2]; pk[7]=(__bf16)v1[3];
            const int byt = (r * 256 + c16 * 16) ^ ((r & 7) << 4);
            *(bf16x8*)((char*)aL + byt) = pk;
        }
        {
            const f32x4* s4 = (const f32x4*)(yb + r * DK + c16 * 8);
            f32x4 v0 = s4[0], v1 = s4[1];
            float s = v0[0]*v0[0] + v0[1]*v0[1] + v0[2]*v0[2] + v0[3]*v0[3]
                    + v1[0]*v1[0] + v1[1]*v1[1] + v1[2]*v1[2] + v1[3]*v1[3];
            s += __shfl_xor(s, 1);
            s += __shfl_xor(s, 2);
            s += __shfl_xor(s, 4);
            s += __shfl_xor(s, 8);
            if (c16 == 0) ysL[r] = s;
            bf16x8 pk;
            pk[0]=(__bf16)v0[0]; pk[1]=(__bf16)v0[1]; pk[2]=(__bf16)v0[2]; pk[3]=(__bf16)v0[3];
            pk[4]=(__bf16)v1[0]; pk[5]=(__bf16)v1[1]; pk[6]=(__bf16)v1[2]; pk[7]=(__bf16)v1[3];
            const int byt = (r * 256 + c16 * 16) ^ ((r & 7) << 4);
            *(bf16x8*)((char*)bL + byt) = pk;
        }
    }
    __syncthreads();

    const int lane = tid & 63;
    const int wid  = tid >> 6;   // 8 waves: 2 (rows) x 4 (cols)
    const int wm   = wid >> 2;   // row group: 64 rows
    const int wn   = wid & 3;    // col group: 32 cols
    const int r16  = lane & 15;
    const int kg   = lane >> 4;

    f32x4 acc[4][2] = {};

#pragma unroll
    for (int ks = 0; ks < 4; ++ks) {
        const int kb = ks * 32 + kg * 8;     // element k-offset for this lane
        bf16x8 af[4], bg[2];
#pragma unroll
        for (int i = 0; i < 4; ++i) {
            const int r = wm * 64 + i * 16 + r16;
            const int byt = (r * 256 + kb * 2) ^ ((r & 7) << 4);
            af[i] = *(const bf16x8*)((const char*)aL + byt);
        }
#pragma unroll
        for (int j = 0; j < 2; ++j) {
            const int r = wn * 32 + j * 16 + r16;
            const int byt = (r * 256 + kb * 2) ^ ((r & 7) << 4);
            bg[j] = *(const bf16x8*)((const char*)bL + byt);
        }
        // Swapped operands: D[row][col] with row from x-tile (A=bg? no —
        // A=y-frag, B=x-frag) so each lane's 4 regs are 4 CONSECUTIVE
        // OUTPUT COLUMNS of one output row -> f32x4 stores.
#pragma unroll
        for (int i = 0; i < 4; ++i)
#pragma unroll
            for (int j = 0; j < 2; ++j)
                acc[i][j] = __builtin_amdgcn_mfma_f32_16x16x32_bf16(bg[j], af[i], acc[i][j], 0, 0, 0);
    }

    // Epilogue. Identity: num_sq = den * s with s = xs + ys - 2*dot,
    // so diff_norm = sqrt(s/den) = s * rsqrt(s*den).
    float* ob = Out + ((size_t)bz * NN + brow) * NN + bcol;
#pragma unroll
    for (int i = 0; i < 4; ++i) {
        const int r = wm * 64 + i * 16 + r16;
        const float u = xsL[r];
        float* orow = ob + (size_t)r * NN;
#pragma unroll
        for (int j = 0; j < 2; ++j) {
            const int cb = wn * 32 + j * 16 + kg * 4;
            const f32x4 v4 = *(const f32x4*)&ysL[cb];
            f32x4 o4;
#pragma unroll
            for (int q = 0; q < 4; ++q) {
                const float d  = acc[i][j][q];
                const float v  = v4[q];
                const float e1 = fmaf(-2.0f, d, 1.0f);      // 1 - 2d
                const float den = fmaf(u, v, e1);           // 1 - 2d + u*v
                float s = fmaf(-2.0f, d, u + v);            // u + v - 2d
                s = fmaxf(s, 1e-12f);
                const float t  = s * den;
                const float dn0 = s * __builtin_amdgcn_rsqf(t);   // sqrt(s/den)
                const float dn = fminf(dn0, NMAX);
                // 2*atanh(z) = ln((1+z)/(1-z))
                o4[q] = __logf((1.0f + dn) * __builtin_amdgcn_rcpf(1.0f - dn));
            }
            *(f32x4*)(orow + cb) = o4;
        }
    }
}

extern "C" void kernel_launch(void* const* d_in, const int* in_sizes, int n_in,
                              void* d_out, int out_size, void* d_ws, size_t ws_size,
                              hipStream_t stream) {
    const float* X = (const float*)d_in[0];
    const float* Y = (const float*)d_in[1];
    float* O = (float*)d_out;
    const int b = in_sizes[0] / (NN * DK);   // = 4
    dim3 grid(NN / BN, NN / BM, b);
    hyp_dist_kernel<<<grid, dim3(512), 0, stream>>>(X, Y, O);
}